// Round 7
// baseline (892.553 us; speedup 1.0000x reference)
//
#include <hip/hip_runtime.h>
#include <stdint.h>

typedef unsigned short u16;
typedef unsigned int   u32;
typedef __bf16 bf16x8 __attribute__((ext_vector_type(8)));
typedef float  f32x4  __attribute__((ext_vector_type(4)));
typedef u16    u16x8  __attribute__((ext_vector_type(8)));
typedef u16    u16x4  __attribute__((ext_vector_type(4)));

// Problem dims
#define NB    4
#define NS    4096
#define NHID  2048
#define NHEAD 16
#define HDIM  128
#define NKT   32    // K-tiles of 64 (K=2048)

__device__ __forceinline__ u16 f2bf(float f) {
  u32 u = __builtin_bit_cast(u32, f);
  u = (u + 0x7fffu + ((u >> 16) & 1u)) >> 16;
  return (u16)u;
}
__device__ __forceinline__ float bf2f(u16 h) {
  return __builtin_bit_cast(float, ((u32)h) << 16);
}

__device__ __forceinline__ void async_copy16(u16* lds_dst, const u16* g_src) {
  __builtin_amdgcn_global_load_lds(
      (__attribute__((address_space(1))) u32*)(const_cast<u16*>(g_src)),
      (__attribute__((address_space(3))) u32*)(lds_dst),
      16, 0, 0);
}

// ===========================================================================
// 4-phase/K-tile 256x256 GEMM core (m201-class), BK=64, 8 waves (2M x 4N).
// 2 LDS buffers x (A 32KB + B 32KB) = 128KB.
// LDS layout per operand/buffer: [kh:2][row:256][gg:4] 16B units; swizzle
// gg ^= (row&3) -> each ds_read_b128 wave hits every bank exactly 8x (floor).
// Stage via pre-swizzled GLOBAL source, linear LDS dest (m173).
//
// RACE FIX vs r6: every consume-read is certified by a (vmcnt -> s_barrier)
// pair executed by ALL waves strictly before the read. Phase order:
//   {8 ds_read (certified data) ; stage 1 half ; [vmcnt] ; barrier ; 16 MFMA}
// Stage per tile t (into buf[(t+1)&1]): P0:A0' P1:B0' P2:A1' P3:B1'.
// FIFO ledger (loads/thread, groups of 2):
//   enter P0: [A1,B1]; P1 after issue: 8 -> vmcnt(4) retires A1,B1 (P2/P3's
//   data); P3 after issue: 8 -> vmcnt(4) retires A0',B0' (next P0/P1's data).
// Counted waits never drain in steady state (T3+T4). Last tile peeled:
// P1 drains vmcnt(0). WAR: last read of any region is >=2 barriers before
// its overwrite issue (per-wave MFMA consumption orders the ds_reads).
// ===========================================================================
__device__ __forceinline__ void stage_half(u16* dst, const u16* src, int tid)
{
#pragma unroll
  for (int i = 0; i < 2; ++i) {
    const int u = (i << 9) + tid;          // [0,1024) 16B units; 4 per row
    const int r = u >> 2, gg = u & 3;
    const int col = ((gg ^ (r & 3)) << 3); // inverse-swizzled source column
    async_copy16(dst + u * 8, src + (size_t)r * 2048 + col);
  }
}

template<int VM, int MH, int KH, bool SWAP>
__device__ __forceinline__ void phase8(const u16* Ac, const u16* Bc,
                                       bool stg, u16* sdst, const u16* ssrc,
                                       f32x4 (&acc)[8][4],
                                       int tid, int wr, int wc, int lr, int ggx)
{
  // ds_reads: data certified landed by the PREVIOUS phase's vmcnt+barrier
  bf16x8 aR[4], bR[4];
#pragma unroll
  for (int m = 0; m < 4; ++m)
    aR[m] = *(const bf16x8*)(Ac + KH * 8192 + ((wr << 7) + MH * 64 + (m << 4) + lr) * 32 + ggx);
#pragma unroll
  for (int n = 0; n < 4; ++n)
    bR[n] = *(const bf16x8*)(Bc + KH * 8192 + ((wc << 6) + (n << 4) + lr) * 32 + ggx);

  if (stg) stage_half(sdst, ssrc, tid);

  if constexpr (VM >= 0) {
    asm volatile("s_waitcnt vmcnt(%0)" :: "n"(VM) : "memory");
  }
  __builtin_amdgcn_sched_barrier(0);
  __builtin_amdgcn_s_barrier();
  __builtin_amdgcn_sched_barrier(0);

  __builtin_amdgcn_s_setprio(1);
#pragma unroll
  for (int m = 0; m < 4; ++m)
#pragma unroll
    for (int n = 0; n < 4; ++n) {
      if (SWAP)
        acc[MH * 4 + m][n] = __builtin_amdgcn_mfma_f32_16x16x32_bf16(bR[n], aR[m], acc[MH * 4 + m][n], 0, 0, 0);
      else
        acc[MH * 4 + m][n] = __builtin_amdgcn_mfma_f32_16x16x32_bf16(aR[m], bR[n], acc[MH * 4 + m][n], 0, 0, 0);
    }
  __builtin_amdgcn_s_setprio(0);
}

template<bool SWAP>
__device__ __forceinline__ void gemm8(const u16* __restrict__ A,
                                      const u16* __restrict__ B,
                                      f32x4 (&acc)[8][4],
                                      u16 (*LA)[16384], u16 (*LB)[16384])
{
  const int tid = threadIdx.x, lane = tid & 63, w = tid >> 6;
  const int wr = w >> 2, wc = w & 3, lg = lane >> 4, lr = lane & 15;
  const int ggx = ((lg ^ (lr & 3)) << 3);

#pragma unroll
  for (int m = 0; m < 8; ++m)
#pragma unroll
    for (int n = 0; n < 4; ++n) acc[m][n] = f32x4{0.f, 0.f, 0.f, 0.f};

  // prologue: full tile 0 -> buf0 (FIFO [A0,B0,A1,B1]); certify A0,B0
  stage_half(LA[0],        A,      tid);
  stage_half(LB[0],        B,      tid);
  stage_half(LA[0] + 8192, A + 32, tid);
  stage_half(LB[0] + 8192, B + 32, tid);
  asm volatile("s_waitcnt vmcnt(4)" ::: "memory");
  __builtin_amdgcn_sched_barrier(0);
  __builtin_amdgcn_s_barrier();
  __builtin_amdgcn_sched_barrier(0);

#pragma unroll 1
  for (int t = 0; t < NKT - 1; ++t) {
    const u16* Ac = LA[t & 1];
    const u16* Bc = LB[t & 1];
    u16* An = LA[(t + 1) & 1];
    u16* Bn = LB[(t + 1) & 1];
    const u16* As  = A + (t + 1) * 64;
    const u16* Bsr = B + (t + 1) * 64;
    phase8<-1, 0, 0, SWAP>(Ac, Bc, true, An,        As,       acc, tid, wr, wc, lr, ggx);
    phase8< 4, 1, 0, SWAP>(Ac, Bc, true, Bn,        Bsr,      acc, tid, wr, wc, lr, ggx);
    phase8<-1, 0, 1, SWAP>(Ac, Bc, true, An + 8192, As + 32,  acc, tid, wr, wc, lr, ggx);
    phase8< 4, 1, 1, SWAP>(Ac, Bc, true, Bn + 8192, Bsr + 32, acc, tid, wr, wc, lr, ggx);
  }
  {  // last tile (t = NKT-1, odd -> buf1), no staging; P1 drains
    const u16* Ac = LA[(NKT - 1) & 1];
    const u16* Bc = LB[(NKT - 1) & 1];
    phase8<-1, 0, 0, SWAP>(Ac, Bc, false, nullptr, nullptr, acc, tid, wr, wc, lr, ggx);
    phase8< 0, 1, 0, SWAP>(Ac, Bc, false, nullptr, nullptr, acc, tid, wr, wc, lr, ggx);
    phase8<-1, 0, 1, SWAP>(Ac, Bc, false, nullptr, nullptr, acc, tid, wr, wc, lr, ggx);
    phase8<-1, 1, 1, SWAP>(Ac, Bc, false, nullptr, nullptr, acc, tid, wr, wc, lr, ggx);
  }
}

// ---------------------------------------------------------------------------
// GEMM1: qkvg = x_bf16 [16384,2048] @ WTcat^T [8192,2048], +bias.
// q,g (swapped-C) -> [s][2048], 8B stores (sigmoid on g);
// k,v (normal-C)  -> directly transposed [bh][d][s], 8B stores.
// grid: 2048 blocks (64 mt x 32 nt), 16x16 supergroups for L2.
// ---------------------------------------------------------------------------
__global__ __launch_bounds__(512, 2) void k_gemm_qkvg(
    const u16* __restrict__ xb, const u16* __restrict__ WT,
    const float* __restrict__ bias,
    u16* __restrict__ q, u16* __restrict__ kT, u16* __restrict__ vT,
    u16* __restrict__ g)
{
  __shared__ u16 LA[2][16384];
  __shared__ u16 LB[2][16384];
  const int bid = blockIdx.x;
  const int grp = bid >> 8, r = bid & 255;
  const int mt = ((grp & 3) << 4) + (r & 15);
  const int nt = ((grp >> 2) << 4) + (r >> 4);
  const size_t bm0 = (size_t)mt << 8;
  const int    bn0 = nt << 8;
  const int nblk = bn0 >> 11;          // 0=q 1=k 2=v 3=g
  const int ocol0 = bn0 & 2047;

  const int tid = threadIdx.x, lane = tid & 63, w = tid >> 6;
  const int wr = w >> 2, wc = w & 3, lg = lane >> 4, lr = lane & 15;

  f32x4 acc[8][4];
  const u16* Ap = xb + bm0 * NHID;
  const u16* Bp = WT + (size_t)bn0 * NHID;

  if (nblk == 0 || nblk == 3) {
    gemm8<true>(Ap, Bp, acc, LA, LB);
    u16* outp = (nblk == 0) ? q : g;
    const bool sig = (nblk == 3);
#pragma unroll
    for (int m = 0; m < 8; ++m) {
      const size_t row = bm0 + (wr << 7) + (m << 4) + lr;
#pragma unroll
      for (int n = 0; n < 4; ++n) {
        const int colb = (wc << 6) + (n << 4) + (lg << 2);
        const float* bp = bias + bn0 + colb;
        u16x4 o;
#pragma unroll
        for (int j = 0; j < 4; ++j) {
          float val = acc[m][n][j] + bp[j];
          if (sig) val = 1.f / (1.f + __expf(-val));
          o[j] = f2bf(val);
        }
        *(u16x4*)(outp + row * NHID + ocol0 + colb) = o;
      }
    }
  } else {
    gemm8<false>(Ap, Bp, acc, LA, LB);
    u16* outp = (nblk == 1) ? kT : vT;
    const int b = (int)(bm0 >> 12);
    const int srow0 = (int)(bm0 & 4095) + (wr << 7) + (lg << 2);
#pragma unroll
    for (int m = 0; m < 8; ++m) {
      const int srow = srow0 + (m << 4);
#pragma unroll
      for (int n = 0; n < 4; ++n) {
        const int cg = ocol0 + (wc << 6) + (n << 4) + lr;  // col in [0,2048)
        const int h = cg >> 7, d = cg & 127;
        const float bia = bias[bn0 + (wc << 6) + (n << 4) + lr];
        u16x4 o;
#pragma unroll
        for (int j = 0; j < 4; ++j) o[j] = f2bf(acc[m][n][j] + bia);
        *(u16x4*)(outp + (((size_t)(b * NHEAD + h) * HDIM + d) << 12) + srow) = o;
      }
    }
  }
}

// ---------------------------------------------------------------------------
// out = attn @ WoT^T + bo (fp32, swapped-C -> float4 stores)
// grid: 512 blocks (64 mt x 8 nt), 16x8 supergroups
// ---------------------------------------------------------------------------
__global__ __launch_bounds__(512, 2) void k_gemm_out(
    const u16* __restrict__ attn, const u16* __restrict__ WoT,
    const float* __restrict__ bo, float* __restrict__ out)
{
  __shared__ u16 LA[2][16384];
  __shared__ u16 LB[2][16384];
  const int bid = blockIdx.x;
  const int grp = bid >> 7, rr = bid & 127;
  const int mt = (grp << 4) + (rr & 15);
  const int nt = rr >> 4;
  const size_t bm0 = (size_t)mt << 8;
  const int    bn0 = nt << 8;

  const int tid = threadIdx.x, lane = tid & 63, w = tid >> 6;
  const int wr = w >> 2, wc = w & 3, lg = lane >> 4, lr = lane & 15;

  f32x4 acc[8][4];
  gemm8<true>(attn + bm0 * NHID, WoT + (size_t)bn0 * NHID, acc, LA, LB);

#pragma unroll
  for (int m = 0; m < 8; ++m) {
    const size_t row = bm0 + (wr << 7) + (m << 4) + lr;
#pragma unroll
    for (int n = 0; n < 4; ++n) {
      const int colb = bn0 + (wc << 6) + (n << 4) + (lg << 2);
      f32x4 o;
#pragma unroll
      for (int j = 0; j < 4; ++j) o[j] = acc[m][n][j] + bo[colb + j];
      *(f32x4*)(out + row * NHID + colb) = o;
    }
  }
}

// ===========================================================================
// Small 128x128 GEMM core (round-0 verified) for the tiny per-head GEMMs
// ===========================================================================
__device__ __forceinline__ void gemm_core(const u16* A, int lda,
                                          const u16* B, int ldb,
                                          int K, f32x4 acc[4][4],
                                          u16* As, u16* Bs)
{
  const int tid  = threadIdx.x;
  const int lane = tid & 63;
  const int w    = tid >> 6;
  const int wr   = (w >> 1) << 6;
  const int wc   = (w & 1) << 6;
  const int lg   = lane >> 4;
  const int lr   = lane & 15;

#pragma unroll
  for (int m = 0; m < 4; ++m)
#pragma unroll
    for (int n = 0; n < 4; ++n) acc[m][n] = f32x4{0.f, 0.f, 0.f, 0.f};

  for (int k0 = 0; k0 < K; k0 += 32) {
#pragma unroll
    for (int issue = 0; issue < 2; ++issue) {
      int c   = issue * 256 + tid;
      int row = c >> 2, cc = (c & 3) << 3;
      async_copy16(As + c * 8, A + (size_t)row * lda + k0 + cc);
    }
#pragma unroll
    for (int issue = 0; issue < 2; ++issue) {
      int c   = issue * 256 + tid;
      int row = c >> 2, cc = (c & 3) << 3;
      async_copy16(Bs + c * 8, B + (size_t)row * ldb + k0 + cc);
    }
    __syncthreads();

    bf16x8 af[4], bv[4];
#pragma unroll
    for (int m = 0; m < 4; ++m)
      af[m] = *(const bf16x8*)(As + ((wr + m * 16 + lr) << 5) + (lg << 3));
#pragma unroll
    for (int n = 0; n < 4; ++n)
      bv[n] = *(const bf16x8*)(Bs + ((wc + n * 16 + lr) << 5) + (lg << 3));

#pragma unroll
    for (int m = 0; m < 4; ++m)
#pragma unroll
      for (int n = 0; n < 4; ++n)
        acc[m][n] = __builtin_amdgcn_mfma_f32_16x16x32_bf16(af[m], bv[n], acc[m][n], 0, 0, 0);

    __syncthreads();
  }
}

// ---------------------------------------------------------------------------
// kv partial: C[e][d] = sum_{s chunk} vT[e][s]*kT[d][s]; grid (64 bh, 8 split)
// ---------------------------------------------------------------------------
__global__ __launch_bounds__(256) void k_gemm_kv(
    const u16* __restrict__ vT, const u16* __restrict__ kT, float* __restrict__ part)
{
  __shared__ u16 As[128 * 32];
  __shared__ u16 Bs[128 * 32];
  const int bh = blockIdx.x, sp = blockIdx.y;
  const u16* A  = vT + (size_t)bh * (HDIM * NS) + sp * 512;
  const u16* Bt = kT + (size_t)bh * (HDIM * NS) + sp * 512;
  f32x4 acc[4][4];
  gemm_core(A, NS, Bt, NS, 512, acc, As, Bs);

  float* outp = part + ((size_t)sp * 64 + bh) * 16384;
  const int tid = threadIdx.x, lane = tid & 63, w = tid >> 6;
  const int wr = (w >> 1) << 6, wc = (w & 1) << 6, lg = lane >> 4, lr = lane & 15;
#pragma unroll
  for (int m = 0; m < 4; ++m)
#pragma unroll
    for (int n = 0; n < 4; ++n) {
      const int col = wc + n * 16 + lr;
#pragma unroll
      for (int j = 0; j < 4; ++j) {
        const int row = wr + m * 16 + lg * 4 + j;
        outp[row * 128 + col] = acc[m][n][j];
      }
    }
}

// ---------------------------------------------------------------------------
// attn = (q @ kv) * g ; grid (32 stiles, 64 bh)
// ---------------------------------------------------------------------------
__global__ __launch_bounds__(256) void k_gemm_attn(
    const u16* __restrict__ q, const u16* __restrict__ kvT,
    const u16* __restrict__ g, u16* __restrict__ attn)
{
  __shared__ u16 As[128 * 32];
  __shared__ u16 Bs[128 * 32];
  const int st = blockIdx.x, bh = blockIdx.y;
  const int b = bh >> 4, h = bh & 15;
  const size_t bs0 = (size_t)b * NS + st * 128;
  f32x4 acc[4][4];
  gemm_core(q + bs0 * NHID + h * HDIM, NHID, kvT + (size_t)bh * 16384, HDIM, HDIM, acc, As, Bs);

  const int tid = threadIdx.x, lane = tid & 63, w = tid >> 6;
  const int wr = (w >> 1) << 6, wc = (w & 1) << 6, lg = lane >> 4, lr = lane & 15;
#pragma unroll
  for (int m = 0; m < 4; ++m)
#pragma unroll
    for (int n = 0; n < 4; ++n) {
      const int col = wc + n * 16 + lr;
#pragma unroll
      for (int j = 0; j < 4; ++j) {
        const int row = wr + m * 16 + lg * 4 + j;
        const size_t idx = (bs0 + row) * NHID + h * HDIM + col;
        attn[idx] = f2bf(acc[m][n][j] * bf2f(g[idx]));
      }
    }
}

// ---------------------------------------------------------------------------
// x fp32 -> bf16
// ---------------------------------------------------------------------------
__global__ __launch_bounds__(256) void k_cvt_x(const float* __restrict__ x, u16* __restrict__ xb)
{
  const size_t i = (size_t)blockIdx.x * 256 + threadIdx.x;
  const float4* xf = (const float4*)x;
  float4 a = xf[2 * i];
  float4 b = xf[2 * i + 1];
  u16x8 o;
  o[0] = f2bf(a.x); o[1] = f2bf(a.y); o[2] = f2bf(a.z); o[3] = f2bf(a.w);
  o[4] = f2bf(b.x); o[5] = f2bf(b.y); o[6] = f2bf(b.z); o[7] = f2bf(b.w);
  ((u16x8*)xb)[i] = o;
}

// ---------------------------------------------------------------------------
// W [2048][2048] fp32 -> WT bf16 transposed
// ---------------------------------------------------------------------------
__global__ __launch_bounds__(256) void k_cvt_w_t(const float* __restrict__ W, u16* __restrict__ WT)
{
  __shared__ u16 t[64][72];
  const int kt = blockIdx.x, nt = blockIdx.y;
  const int tid = threadIdx.x;
#pragma unroll
  for (int pass = 0; pass < 4; ++pass) {
    int c = pass * 256 + tid;
    int r = c >> 4, cc = (c & 15) << 2;
    float4 vv = *(const float4*)(W + (size_t)(kt * 64 + r) * 2048 + nt * 64 + cc);
    u16x4 o;
    o[0] = f2bf(vv.x); o[1] = f2bf(vv.y); o[2] = f2bf(vv.z); o[3] = f2bf(vv.w);
    *(u16x4*)&t[r][cc] = o;
  }
  __syncthreads();
#pragma unroll
  for (int pass = 0; pass < 2; ++pass) {
    int c = pass * 256 + tid;
    int rn = c >> 3, cs = (c & 7) << 3;
    u16x8 o;
#pragma unroll
    for (int j = 0; j < 8; ++j) o[j] = t[cs + j][rn];
    *(u16x8*)(WT + (size_t)(nt * 64 + rn) * 2048 + kt * 64 + cs) = o;
  }
}

// ---------------------------------------------------------------------------
__global__ __launch_bounds__(256) void k_bias_cat(
    const float* __restrict__ bq, const float* __restrict__ bk,
    const float* __restrict__ bv, const float* __restrict__ bg, float* __restrict__ o)
{
  const int i = blockIdx.x * 256 + threadIdx.x;  // 8192
  const int blk = i >> 11;
  const float* s = (blk == 0) ? bq : (blk == 1) ? bk : (blk == 2) ? bv : bg;
  o[i] = s[i & 2047];
}

__global__ __launch_bounds__(256) void k_kv_reduce(const float* __restrict__ part, u16* __restrict__ kvT)
{
  const int i = blockIdx.x * 256 + threadIdx.x;  // 1,048,576
  float s = 0.f;
#pragma unroll
  for (int sp = 0; sp < 8; ++sp) s += part[(size_t)sp * 1048576 + i];
  kvT[i] = f2bf(s);
}

// ---------------------------------------------------------------------------
extern "C" void kernel_launch(void* const* d_in, const int* in_sizes, int n_in,
                              void* d_out, int out_size, void* d_ws, size_t ws_size,
                              hipStream_t stream)
{
  const float* x  = (const float*)d_in[0];
  const float* Wq = (const float*)d_in[1];
  const float* bq = (const float*)d_in[2];
  const float* Wk = (const float*)d_in[3];
  const float* bk = (const float*)d_in[4];
  const float* Wv = (const float*)d_in[5];
  const float* bv = (const float*)d_in[6];
  const float* Wg = (const float*)d_in[7];
  const float* bg = (const float*)d_in[8];
  const float* Wo = (const float*)d_in[9];
  const float* bo = (const float*)d_in[10];
  float* out = (float*)d_out;

  char* ws = (char*)d_ws;
  u16*   xb   = (u16*)(ws + 0x00000000ULL);  // 64MB
  u16*   WT   = (u16*)(ws + 0x04000000ULL);  // 32MB  [Wq|Wk|Wv|Wg]^T bf16
  u16*   WoT  = (u16*)(ws + 0x06000000ULL);  // 8MB
  float* bias = (float*)(ws + 0x06800000ULL);// 32KB
  u16*   q    = (u16*)(ws + 0x06900000ULL);  // 64MB
  u16*   kT   = (u16*)(ws + 0x0A900000ULL);  // 64MB  [bh][d][s]
  u16*   vT   = (u16*)(ws + 0x0E900000ULL);  // 64MB  [bh][d][s]
  u16*   gg   = (u16*)(ws + 0x12900000ULL);  // 64MB
  u16*   kvT  = (u16*)(ws + 0x16900000ULL);  // 2MB
  // aliases (producer/consumer disjoint across sequential launches)
  float* part = (float*)WT;   // WT dead after qkvg (exactly 32MB)
  u16*   attn = xb;           // xb dead after qkvg

  if (ws_size < 0x16B00000ULL) return;

  k_cvt_x<<<16384, 256, 0, stream>>>(x, xb);
  k_cvt_w_t<<<dim3(32, 32), 256, 0, stream>>>(Wq, WT);
  k_cvt_w_t<<<dim3(32, 32), 256, 0, stream>>>(Wk, WT + (size_t)2048 * 2048);
  k_cvt_w_t<<<dim3(32, 32), 256, 0, stream>>>(Wv, WT + (size_t)2 * 2048 * 2048);
  k_cvt_w_t<<<dim3(32, 32), 256, 0, stream>>>(Wg, WT + (size_t)3 * 2048 * 2048);
  k_cvt_w_t<<<dim3(32, 32), 256, 0, stream>>>(Wo, WoT);
  k_bias_cat<<<32, 256, 0, stream>>>(bq, bk, bv, bg, bias);

  k_gemm_qkvg<<<2048, 512, 0, stream>>>(xb, WT, bias, q, kT, vT, gg);

  k_gemm_kv<<<dim3(64, 8), 256, 0, stream>>>(vT, kT, part);
  k_kv_reduce<<<4096, 256, 0, stream>>>(part, kvT);

  k_gemm_attn<<<dim3(32, 64), 256, 0, stream>>>(q, kvT, gg, attn);
  k_gemm_out<<<512, 512, 0, stream>>>(attn, WoT, bo, out);
}

// Round 8
// 876.045 us; speedup vs baseline: 1.0188x; 1.0188x over previous
//
#include <hip/hip_runtime.h>
#include <stdint.h>

typedef unsigned short u16;
typedef unsigned int   u32;
typedef __bf16 bf16x8 __attribute__((ext_vector_type(8)));
typedef float  f32x4  __attribute__((ext_vector_type(4)));
typedef u16    u16x8  __attribute__((ext_vector_type(8)));
typedef u16    u16x4  __attribute__((ext_vector_type(4)));

// Problem dims
#define NB    4
#define NS    4096
#define NHID  2048
#define NHEAD 16
#define HDIM  128
#define NKT   32    // K-tiles of 64 (K=2048)

__device__ __forceinline__ u16 f2bf(float f) {
  u32 u = __builtin_bit_cast(u32, f);
  u = (u + 0x7fffu + ((u >> 16) & 1u)) >> 16;
  return (u16)u;
}
__device__ __forceinline__ float bf2f(u16 h) {
  return __builtin_bit_cast(float, ((u32)h) << 16);
}

__device__ __forceinline__ void async_copy16(u16* lds_dst, const u16* g_src) {
  __builtin_amdgcn_global_load_lds(
      (__attribute__((address_space(1))) u32*)(const_cast<u16*>(g_src)),
      (__attribute__((address_space(3))) u32*)(lds_dst),
      16, 0, 0);
}

// ===========================================================================
// 4-phase/K-tile 256x256 GEMM core, BK=64, 8 waves (2M x 4N).
// 2 LDS buffers x (A 32KB + B 32KB) = 128KB.
// LDS layout per operand/buffer: [kh:2][row:256][gg:4] 16B units.
// Swizzle (r3-VERIFIED function, conflicts=0): gg ^= (row>>1)&3 — period-8
// in row so each 16-lane exec phase has only 2 lanes/start-bank (free).
// (r7's (row&3) variant was 4-way conflicted within 16-lane phases.)
// Stage via pre-swizzled GLOBAL source, linear LDS dest (m173).
//
// Sync skeleton IDENTICAL to r7 (race-verified, passed):
//   phase = {ds_reads (data certified by prev phase's vmcnt+barrier);
//            stage 1 half; [vmcnt]; barrier; 16 MFMA (setprio)}
// Stage per tile t (into buf[(t+1)&1]): P0:A0' P1:B0' P2:A1' P3:B1'.
// FIFO ledger: P1 vmcnt(4) certifies A1,B1 for P2/P3; P3 vmcnt(4)
// certifies A0',B0' for next tile's P0/P1. Peeled last tile: P1 vmcnt(0).
//
// r8 read economy: bR held in registers across the two MH phases of each
// KH half -> 24 ds_read_b128/tile/wave (r7's MH-split re-read cost 32).
// ===========================================================================
__device__ __forceinline__ void stage_half(u16* dst, const u16* src, int tid)
{
#pragma unroll
  for (int i = 0; i < 2; ++i) {
    const int u = (i << 9) + tid;          // [0,1024) 16B units; 4 per row
    const int r = u >> 2, gg = u & 3;
    const int col = ((gg ^ ((r >> 1) & 3)) << 3); // inverse-swizzled src col
    async_copy16(dst + u * 8, src + (size_t)r * 2048 + col);
  }
}

template<int VM, int MH, int KH, bool LOADB, bool STG, bool SWAP>
__device__ __forceinline__ void phase4(const u16* Ac, const u16* Bc,
                                       u16* sdst, const u16* ssrc,
                                       bf16x8 (&bR)[4], f32x4 (&acc)[8][4],
                                       int tid, int wr, int wc, int lr, int ggx)
{
  // ds_reads: data certified landed by the PREVIOUS phase's vmcnt+barrier
  if (LOADB) {
#pragma unroll
    for (int n = 0; n < 4; ++n)
      bR[n] = *(const bf16x8*)(Bc + KH * 8192 + ((wc << 6) + (n << 4) + lr) * 32 + ggx);
  }
  bf16x8 aR[4];
#pragma unroll
  for (int m = 0; m < 4; ++m)
    aR[m] = *(const bf16x8*)(Ac + KH * 8192 + ((wr << 7) + MH * 64 + (m << 4) + lr) * 32 + ggx);

  if (STG) stage_half(sdst, ssrc, tid);

  if constexpr (VM >= 0) {
    asm volatile("s_waitcnt vmcnt(%0)" :: "n"(VM) : "memory");
  }
  __builtin_amdgcn_sched_barrier(0);
  __builtin_amdgcn_s_barrier();
  __builtin_amdgcn_sched_barrier(0);

  __builtin_amdgcn_s_setprio(1);
#pragma unroll
  for (int m = 0; m < 4; ++m)
#pragma unroll
    for (int n = 0; n < 4; ++n) {
      if (SWAP)
        acc[MH * 4 + m][n] = __builtin_amdgcn_mfma_f32_16x16x32_bf16(bR[n], aR[m], acc[MH * 4 + m][n], 0, 0, 0);
      else
        acc[MH * 4 + m][n] = __builtin_amdgcn_mfma_f32_16x16x32_bf16(aR[m], bR[n], acc[MH * 4 + m][n], 0, 0, 0);
    }
  __builtin_amdgcn_s_setprio(0);
}

template<bool SWAP>
__device__ __forceinline__ void gemm8(const u16* __restrict__ A,
                                      const u16* __restrict__ B,
                                      f32x4 (&acc)[8][4],
                                      u16 (*LA)[16384], u16 (*LB)[16384])
{
  const int tid = threadIdx.x, lane = tid & 63, w = tid >> 6;
  const int wr = w >> 2, wc = w & 3, lg = lane >> 4, lr = lane & 15;
  const int ggx = ((lg ^ ((lr >> 1) & 3)) << 3);   // r3-verified read swizzle

#pragma unroll
  for (int m = 0; m < 8; ++m)
#pragma unroll
    for (int n = 0; n < 4; ++n) acc[m][n] = f32x4{0.f, 0.f, 0.f, 0.f};

  // prologue: full tile 0 -> buf0 (FIFO [A0,B0,A1,B1]); certify A0,B0
  stage_half(LA[0],        A,      tid);
  stage_half(LB[0],        B,      tid);
  stage_half(LA[0] + 8192, A + 32, tid);
  stage_half(LB[0] + 8192, B + 32, tid);
  asm volatile("s_waitcnt vmcnt(4)" ::: "memory");
  __builtin_amdgcn_sched_barrier(0);
  __builtin_amdgcn_s_barrier();
  __builtin_amdgcn_sched_barrier(0);

  bf16x8 bR[4];
#pragma unroll 1
  for (int t = 0; t < NKT - 1; ++t) {
    const u16* Ac = LA[t & 1];
    const u16* Bc = LB[t & 1];
    u16* An = LA[(t + 1) & 1];
    u16* Bn = LB[(t + 1) & 1];
    const u16* As  = A + (t + 1) * 64;
    const u16* Bsr = B + (t + 1) * 64;
    phase4<-1, 0, 0, true,  true, SWAP>(Ac, Bc, An,        As,       bR, acc, tid, wr, wc, lr, ggx);
    phase4< 4, 1, 0, false, true, SWAP>(Ac, Bc, Bn,        Bsr,      bR, acc, tid, wr, wc, lr, ggx);
    phase4<-1, 0, 1, true,  true, SWAP>(Ac, Bc, An + 8192, As + 32,  bR, acc, tid, wr, wc, lr, ggx);
    phase4< 4, 1, 1, false, true, SWAP>(Ac, Bc, Bn + 8192, Bsr + 32, bR, acc, tid, wr, wc, lr, ggx);
  }
  {  // last tile (t = NKT-1, odd -> buf1), no staging; P1 drains for P2/P3
    const u16* Ac = LA[(NKT - 1) & 1];
    const u16* Bc = LB[(NKT - 1) & 1];
    phase4<-1, 0, 0, true,  false, SWAP>(Ac, Bc, nullptr, nullptr, bR, acc, tid, wr, wc, lr, ggx);
    phase4< 0, 1, 0, false, false, SWAP>(Ac, Bc, nullptr, nullptr, bR, acc, tid, wr, wc, lr, ggx);
    phase4<-1, 0, 1, true,  false, SWAP>(Ac, Bc, nullptr, nullptr, bR, acc, tid, wr, wc, lr, ggx);
    phase4<-1, 1, 1, false, false, SWAP>(Ac, Bc, nullptr, nullptr, bR, acc, tid, wr, wc, lr, ggx);
  }
}

// ---------------------------------------------------------------------------
// GEMM1: qkvg = x_bf16 [16384,2048] @ WTcat^T [8192,2048], +bias.
// q,g (swapped-C) -> [s][2048], 8B stores (sigmoid on g);
// k,v (normal-C)  -> directly transposed [bh][d][s], 8B stores.
// grid: 2048 blocks (64 mt x 32 nt), 16x16 supergroups for L2.
// ---------------------------------------------------------------------------
__global__ __launch_bounds__(512, 2) void k_gemm_qkvg(
    const u16* __restrict__ xb, const u16* __restrict__ WT,
    const float* __restrict__ bias,
    u16* __restrict__ q, u16* __restrict__ kT, u16* __restrict__ vT,
    u16* __restrict__ g)
{
  __shared__ u16 LA[2][16384];
  __shared__ u16 LB[2][16384];
  const int bid = blockIdx.x;
  const int grp = bid >> 8, r = bid & 255;
  const int mt = ((grp & 3) << 4) + (r & 15);
  const int nt = ((grp >> 2) << 4) + (r >> 4);
  const size_t bm0 = (size_t)mt << 8;
  const int    bn0 = nt << 8;
  const int nblk = bn0 >> 11;          // 0=q 1=k 2=v 3=g
  const int ocol0 = bn0 & 2047;

  const int tid = threadIdx.x, lane = tid & 63, w = tid >> 6;
  const int wr = w >> 2, wc = w & 3, lg = lane >> 4, lr = lane & 15;

  f32x4 acc[8][4];
  const u16* Ap = xb + bm0 * NHID;
  const u16* Bp = WT + (size_t)bn0 * NHID;

  if (nblk == 0 || nblk == 3) {
    gemm8<true>(Ap, Bp, acc, LA, LB);
    u16* outp = (nblk == 0) ? q : g;
    const bool sig = (nblk == 3);
#pragma unroll
    for (int m = 0; m < 8; ++m) {
      const size_t row = bm0 + (wr << 7) + (m << 4) + lr;
#pragma unroll
      for (int n = 0; n < 4; ++n) {
        const int colb = (wc << 6) + (n << 4) + (lg << 2);
        const float* bp = bias + bn0 + colb;
        u16x4 o;
#pragma unroll
        for (int j = 0; j < 4; ++j) {
          float val = acc[m][n][j] + bp[j];
          if (sig) val = 1.f / (1.f + __expf(-val));
          o[j] = f2bf(val);
        }
        *(u16x4*)(outp + row * NHID + ocol0 + colb) = o;
      }
    }
  } else {
    gemm8<false>(Ap, Bp, acc, LA, LB);
    u16* outp = (nblk == 1) ? kT : vT;
    const int b = (int)(bm0 >> 12);
    const int srow0 = (int)(bm0 & 4095) + (wr << 7) + (lg << 2);
#pragma unroll
    for (int m = 0; m < 8; ++m) {
      const int srow = srow0 + (m << 4);
#pragma unroll
      for (int n = 0; n < 4; ++n) {
        const int cg = ocol0 + (wc << 6) + (n << 4) + lr;  // col in [0,2048)
        const int h = cg >> 7, d = cg & 127;
        const float bia = bias[bn0 + (wc << 6) + (n << 4) + lr];
        u16x4 o;
#pragma unroll
        for (int j = 0; j < 4; ++j) o[j] = f2bf(acc[m][n][j] + bia);
        *(u16x4*)(outp + (((size_t)(b * NHEAD + h) * HDIM + d) << 12) + srow) = o;
      }
    }
  }
}

// ---------------------------------------------------------------------------
// out = attn @ WoT^T + bo (fp32, swapped-C -> float4 stores)
// grid: 512 blocks (64 mt x 8 nt), 16x8 supergroups
// ---------------------------------------------------------------------------
__global__ __launch_bounds__(512, 2) void k_gemm_out(
    const u16* __restrict__ attn, const u16* __restrict__ WoT,
    const float* __restrict__ bo, float* __restrict__ out)
{
  __shared__ u16 LA[2][16384];
  __shared__ u16 LB[2][16384];
  const int bid = blockIdx.x;
  const int grp = bid >> 7, rr = bid & 127;
  const int mt = (grp << 4) + (rr & 15);
  const int nt = rr >> 4;
  const size_t bm0 = (size_t)mt << 8;
  const int    bn0 = nt << 8;

  const int tid = threadIdx.x, lane = tid & 63, w = tid >> 6;
  const int wr = w >> 2, wc = w & 3, lg = lane >> 4, lr = lane & 15;

  f32x4 acc[8][4];
  gemm8<true>(attn + bm0 * NHID, WoT + (size_t)bn0 * NHID, acc, LA, LB);

#pragma unroll
  for (int m = 0; m < 8; ++m) {
    const size_t row = bm0 + (wr << 7) + (m << 4) + lr;
#pragma unroll
    for (int n = 0; n < 4; ++n) {
      const int colb = bn0 + (wc << 6) + (n << 4) + (lg << 2);
      f32x4 o;
#pragma unroll
      for (int j = 0; j < 4; ++j) o[j] = acc[m][n][j] + bo[colb + j];
      *(f32x4*)(out + row * NHID + colb) = o;
    }
  }
}

// ===========================================================================
// Small 128x128 GEMM core (round-0 verified) for the tiny per-head GEMMs
// ===========================================================================
__device__ __forceinline__ void gemm_core(const u16* A, int lda,
                                          const u16* B, int ldb,
                                          int K, f32x4 acc[4][4],
                                          u16* As, u16* Bs)
{
  const int tid  = threadIdx.x;
  const int lane = tid & 63;
  const int w    = tid >> 6;
  const int wr   = (w >> 1) << 6;
  const int wc   = (w & 1) << 6;
  const int lg   = lane >> 4;
  const int lr   = lane & 15;

#pragma unroll
  for (int m = 0; m < 4; ++m)
#pragma unroll
    for (int n = 0; n < 4; ++n) acc[m][n] = f32x4{0.f, 0.f, 0.f, 0.f};

  for (int k0 = 0; k0 < K; k0 += 32) {
#pragma unroll
    for (int issue = 0; issue < 2; ++issue) {
      int c   = issue * 256 + tid;
      int row = c >> 2, cc = (c & 3) << 3;
      async_copy16(As + c * 8, A + (size_t)row * lda + k0 + cc);
    }
#pragma unroll
    for (int issue = 0; issue < 2; ++issue) {
      int c   = issue * 256 + tid;
      int row = c >> 2, cc = (c & 3) << 3;
      async_copy16(Bs + c * 8, B + (size_t)row * ldb + k0 + cc);
    }
    __syncthreads();

    bf16x8 af[4], bv[4];
#pragma unroll
    for (int m = 0; m < 4; ++m)
      af[m] = *(const bf16x8*)(As + ((wr + m * 16 + lr) << 5) + (lg << 3));
#pragma unroll
    for (int n = 0; n < 4; ++n)
      bv[n] = *(const bf16x8*)(Bs + ((wc + n * 16 + lr) << 5) + (lg << 3));

#pragma unroll
    for (int m = 0; m < 4; ++m)
#pragma unroll
      for (int n = 0; n < 4; ++n)
        acc[m][n] = __builtin_amdgcn_mfma_f32_16x16x32_bf16(af[m], bv[n], acc[m][n], 0, 0, 0);

    __syncthreads();
  }
}

// ---------------------------------------------------------------------------
// kv partial: C[e][d] = sum_{s chunk} vT[e][s]*kT[d][s]; grid (64 bh, 8 split)
// ---------------------------------------------------------------------------
__global__ __launch_bounds__(256) void k_gemm_kv(
    const u16* __restrict__ vT, const u16* __restrict__ kT, float* __restrict__ part)
{
  __shared__ u16 As[128 * 32];
  __shared__ u16 Bs[128 * 32];
  const int bh = blockIdx.x, sp = blockIdx.y;
  const u16* A  = vT + (size_t)bh * (HDIM * NS) + sp * 512;
  const u16* Bt = kT + (size_t)bh * (HDIM * NS) + sp * 512;
  f32x4 acc[4][4];
  gemm_core(A, NS, Bt, NS, 512, acc, As, Bs);

  float* outp = part + ((size_t)sp * 64 + bh) * 16384;
  const int tid = threadIdx.x, lane = tid & 63, w = tid >> 6;
  const int wr = (w >> 1) << 6, wc = (w & 1) << 6, lg = lane >> 4, lr = lane & 15;
#pragma unroll
  for (int m = 0; m < 4; ++m)
#pragma unroll
    for (int n = 0; n < 4; ++n) {
      const int col = wc + n * 16 + lr;
#pragma unroll
      for (int j = 0; j < 4; ++j) {
        const int row = wr + m * 16 + lg * 4 + j;
        outp[row * 128 + col] = acc[m][n][j];
      }
    }
}

// ---------------------------------------------------------------------------
// attn = (q @ kv) * g ; grid (32 stiles, 64 bh)
// ---------------------------------------------------------------------------
__global__ __launch_bounds__(256) void k_gemm_attn(
    const u16* __restrict__ q, const u16* __restrict__ kvT,
    const u16* __restrict__ g, u16* __restrict__ attn)
{
  __shared__ u16 As[128 * 32];
  __shared__ u16 Bs[128 * 32];
  const int st = blockIdx.x, bh = blockIdx.y;
  const int b = bh >> 4, h = bh & 15;
  const size_t bs0 = (size_t)b * NS + st * 128;
  f32x4 acc[4][4];
  gemm_core(q + bs0 * NHID + h * HDIM, NHID, kvT + (size_t)bh * 16384, HDIM, HDIM, acc, As, Bs);

  const int tid = threadIdx.x, lane = tid & 63, w = tid >> 6;
  const int wr = (w >> 1) << 6, wc = (w & 1) << 6, lg = lane >> 4, lr = lane & 15;
#pragma unroll
  for (int m = 0; m < 4; ++m)
#pragma unroll
    for (int n = 0; n < 4; ++n) {
      const int col = wc + n * 16 + lr;
#pragma unroll
      for (int j = 0; j < 4; ++j) {
        const int row = wr + m * 16 + lg * 4 + j;
        const size_t idx = (bs0 + row) * NHID + h * HDIM + col;
        attn[idx] = f2bf(acc[m][n][j] * bf2f(g[idx]));
      }
    }
}

// ---------------------------------------------------------------------------
// x fp32 -> bf16
// ---------------------------------------------------------------------------
__global__ __launch_bounds__(256) void k_cvt_x(const float* __restrict__ x, u16* __restrict__ xb)
{
  const size_t i = (size_t)blockIdx.x * 256 + threadIdx.x;
  const float4* xf = (const float4*)x;
  float4 a = xf[2 * i];
  float4 b = xf[2 * i + 1];
  u16x8 o;
  o[0] = f2bf(a.x); o[1] = f2bf(a.y); o[2] = f2bf(a.z); o[3] = f2bf(a.w);
  o[4] = f2bf(b.x); o[5] = f2bf(b.y); o[6] = f2bf(b.z); o[7] = f2bf(b.w);
  ((u16x8*)xb)[i] = o;
}

// ---------------------------------------------------------------------------
// W [2048][2048] fp32 -> WT bf16 transposed
// ---------------------------------------------------------------------------
__global__ __launch_bounds__(256) void k_cvt_w_t(const float* __restrict__ W, u16* __restrict__ WT)
{
  __shared__ u16 t[64][72];
  const int kt = blockIdx.x, nt = blockIdx.y;
  const int tid = threadIdx.x;
#pragma unroll
  for (int pass = 0; pass < 4; ++pass) {
    int c = pass * 256 + tid;
    int r = c >> 4, cc = (c & 15) << 2;
    float4 vv = *(const float4*)(W + (size_t)(kt * 64 + r) * 2048 + nt * 64 + cc);
    u16x4 o;
    o[0] = f2bf(vv.x); o[1] = f2bf(vv.y); o[2] = f2bf(vv.z); o[3] = f2bf(vv.w);
    *(u16x4*)&t[r][cc] = o;
  }
  __syncthreads();
#pragma unroll
  for (int pass = 0; pass < 2; ++pass) {
    int c = pass * 256 + tid;
    int rn = c >> 3, cs = (c & 7) << 3;
    u16x8 o;
#pragma unroll
    for (int j = 0; j < 8; ++j) o[j] = t[cs + j][rn];
    *(u16x8*)(WT + (size_t)(nt * 64 + rn) * 2048 + kt * 64 + cs) = o;
  }
}

// ---------------------------------------------------------------------------
__global__ __launch_bounds__(256) void k_bias_cat(
    const float* __restrict__ bq, const float* __restrict__ bk,
    const float* __restrict__ bv, const float* __restrict__ bg, float* __restrict__ o)
{
  const int i = blockIdx.x * 256 + threadIdx.x;  // 8192
  const int blk = i >> 11;
  const float* s = (blk == 0) ? bq : (blk == 1) ? bk : (blk == 2) ? bv : bg;
  o[i] = s[i & 2047];
}

__global__ __launch_bounds__(256) void k_kv_reduce(const float* __restrict__ part, u16* __restrict__ kvT)
{
  const int i = blockIdx.x * 256 + threadIdx.x;  // 1,048,576
  float s = 0.f;
#pragma unroll
  for (int sp = 0; sp < 8; ++sp) s += part[(size_t)sp * 1048576 + i];
  kvT[i] = f2bf(s);
}

// ---------------------------------------------------------------------------
extern "C" void kernel_launch(void* const* d_in, const int* in_sizes, int n_in,
                              void* d_out, int out_size, void* d_ws, size_t ws_size,
                              hipStream_t stream)
{
  const float* x  = (const float*)d_in[0];
  const float* Wq = (const float*)d_in[1];
  const float* bq = (const float*)d_in[2];
  const float* Wk = (const float*)d_in[3];
  const float* bk = (const float*)d_in[4];
  const float* Wv = (const float*)d_in[5];
  const float* bv = (const float*)d_in[6];
  const float* Wg = (const float*)d_in[7];
  const float* bg = (const float*)d_in[8];
  const float* Wo = (const float*)d_in[9];
  const float* bo = (const float*)d_in[10];
  float* out = (float*)d_out;

  char* ws = (char*)d_ws;
  u16*   xb   = (u16*)(ws + 0x00000000ULL);  // 64MB
  u16*   WT   = (u16*)(ws + 0x04000000ULL);  // 32MB  [Wq|Wk|Wv|Wg]^T bf16
  u16*   WoT  = (u16*)(ws + 0x06000000ULL);  // 8MB
  float* bias = (float*)(ws + 0x06800000ULL);// 32KB
  u16*   q    = (u16*)(ws + 0x06900000ULL);  // 64MB
  u16*   kT   = (u16*)(ws + 0x0A900000ULL);  // 64MB  [bh][d][s]
  u16*   vT   = (u16*)(ws + 0x0E900000ULL);  // 64MB  [bh][d][s]
  u16*   gg   = (u16*)(ws + 0x12900000ULL);  // 64MB
  u16*   kvT  = (u16*)(ws + 0x16900000ULL);  // 2MB
  // aliases (producer/consumer disjoint across sequential launches)
  float* part = (float*)WT;   // WT dead after qkvg (exactly 32MB)
  u16*   attn = xb;           // xb dead after qkvg

  if (ws_size < 0x16B00000ULL) return;

  k_cvt_x<<<16384, 256, 0, stream>>>(x, xb);
  k_cvt_w_t<<<dim3(32, 32), 256, 0, stream>>>(Wq, WT);
  k_cvt_w_t<<<dim3(32, 32), 256, 0, stream>>>(Wk, WT + (size_t)2048 * 2048);
  k_cvt_w_t<<<dim3(32, 32), 256, 0, stream>>>(Wv, WT + (size_t)2 * 2048 * 2048);
  k_cvt_w_t<<<dim3(32, 32), 256, 0, stream>>>(Wg, WT + (size_t)3 * 2048 * 2048);
  k_cvt_w_t<<<dim3(32, 32), 256, 0, stream>>>(Wo, WoT);
  k_bias_cat<<<32, 256, 0, stream>>>(bq, bk, bv, bg, bias);

  k_gemm_qkvg<<<2048, 512, 0, stream>>>(xb, WT, bias, q, kT, vT, gg);

  k_gemm_kv<<<dim3(64, 8), 256, 0, stream>>>(vT, kT, part);
  k_kv_reduce<<<4096, 256, 0, stream>>>(part, kvT);

  k_gemm_attn<<<dim3(32, 64), 256, 0, stream>>>(q, kvT, gg, attn);
  k_gemm_out<<<512, 512, 0, stream>>>(attn, WoT, bo, out);
}

// Round 9
// 794.258 us; speedup vs baseline: 1.1238x; 1.1030x over previous
//
#include <hip/hip_runtime.h>
#include <stdint.h>

typedef unsigned short u16;
typedef unsigned int   u32;
typedef __bf16 bf16x8 __attribute__((ext_vector_type(8)));
typedef float  f32x4  __attribute__((ext_vector_type(4)));
typedef u16    u16x8  __attribute__((ext_vector_type(8)));
typedef u16    u16x4  __attribute__((ext_vector_type(4)));

// Problem dims
#define NB    4
#define NS    4096
#define NHID  2048
#define NHEAD 16
#define HDIM  128
#define NKT   32    // K-tiles of 64 (K=2048)

__device__ __forceinline__ u16 f2bf(float f) {
  u32 u = __builtin_bit_cast(u32, f);
  u = (u + 0x7fffu + ((u >> 16) & 1u)) >> 16;
  return (u16)u;
}
__device__ __forceinline__ float bf2f(u16 h) {
  return __builtin_bit_cast(float, ((u32)h) << 16);
}

__device__ __forceinline__ void async_copy16(u16* lds_dst, const u16* g_src) {
  __builtin_amdgcn_global_load_lds(
      (__attribute__((address_space(1))) u32*)(const_cast<u16*>(g_src)),
      (__attribute__((address_space(3))) u32*)(lds_dst),
      16, 0, 0);
}

#define SBAR()  __builtin_amdgcn_sched_barrier(0)
#define BARRIER() do { SBAR(); __builtin_amdgcn_s_barrier(); SBAR(); } while (0)
#define LGKM0() asm volatile("s_waitcnt lgkmcnt(0)" ::: "memory")
#define VM0()   asm volatile("s_waitcnt vmcnt(0)"   ::: "memory")

// ===========================================================================
// r9 core: 256x256 tile, BK=64, 8 waves (2M x 4N), per-wave 128x64.
// PREFETCH-READ WINDOWS: each barrier-to-barrier window executes
//   {[stage]; [vmcnt(0) @W3]; barrier; ds_reads for NEXT window;
//    16 MFMA using regs read LAST window; lgkmcnt(0)}
// so the LDS pipe (next window's reads) and the MFMA pipe (this window's
// cluster) run concurrently instead of serializing (r4-r8 diagnosis).
//
// LDS: 2 buffers x {A[2 M-half][128][64], B[2 half][128][64]} = 128 KB.
// Swizzle: 16B-unit u ^= (row&7) within each 128B row -> every 16-lane read
// phase covers 8 distinct unit-slots = 2 accesses/bank (floor). Stage via
// inverse-permuted GLOBAL source, linear LDS dest (m173).
//
// Ledger: tile t+1 staged at t.W0 (A-h0,B-h0) and t.W1 (A-h1,B-h1) into
// buf[(t+1)&1]; certified by t.W3's vmcnt(0)+barrier; first read of it is
// t.W3's prefetch (after that barrier). Trailing lgkmcnt(0) bounds each
// window's reads to complete before the next barrier, so any region's last
// read strictly precedes its overwrite (>=1 barrier apart). bR regs reused
// across the two mq windows of each kg -> 24 ds_read_b128 / tile / wave.
// ===========================================================================
__device__ __forceinline__ void stage9(u16* dst, const u16* src, int kt, int tid)
{
#pragma unroll
  for (int i = 0; i < 2; ++i) {
    const int U = (i << 9) + tid;            // [0,1024) 16B units, 8 per row
    const int r = U >> 3, u = U & 7;
    const int col = (kt << 6) + ((u ^ (r & 7)) << 3);  // inverse-swizzled src
    async_copy16(dst + U * 8, src + (size_t)r * 2048 + col);
  }
}

__device__ __forceinline__ void rd_a(bf16x8 (&d)[4], const u16* base,
                                     int kg, int mq, int lg, int lr)
{
#pragma unroll
  for (int m = 0; m < 4; ++m) {
    const int row = (mq << 6) + (m << 4) + lr;
    const int c = ((kg << 2) | lg) ^ (row & 7);
    d[m] = *(const bf16x8*)(base + row * 64 + (c << 3));
  }
}

__device__ __forceinline__ void rd_b(bf16x8 (&d)[4], const u16* base,
                                     int kg, int lg, int lr)
{
#pragma unroll
  for (int n = 0; n < 4; ++n) {
    const int row = (n << 4) + lr;           // base folds (wc&1)*64 rows
    const int c = ((kg << 2) | lg) ^ (row & 7);
    d[n] = *(const bf16x8*)(base + row * 64 + (c << 3));
  }
}

template<bool SWAP>
__device__ __forceinline__ void mmcl(f32x4 (&acc)[8][4], int mq,
                                     const bf16x8 (&a)[4], const bf16x8 (&b)[4])
{
  __builtin_amdgcn_s_setprio(1);
#pragma unroll
  for (int mm = 0; mm < 4; ++mm)
#pragma unroll
    for (int n = 0; n < 4; ++n) {
      if (SWAP)
        acc[mq * 4 + mm][n] = __builtin_amdgcn_mfma_f32_16x16x32_bf16(b[n], a[mm], acc[mq * 4 + mm][n], 0, 0, 0);
      else
        acc[mq * 4 + mm][n] = __builtin_amdgcn_mfma_f32_16x16x32_bf16(a[mm], b[n], acc[mq * 4 + mm][n], 0, 0, 0);
    }
  __builtin_amdgcn_s_setprio(0);
}

template<bool SWAP>
__device__ __forceinline__ void gemm9(const u16* __restrict__ A,
                                      const u16* __restrict__ B,
                                      f32x4 (&acc)[8][4], u16* L)
{
  const int tid = threadIdx.x, lane = tid & 63, w = tid >> 6;
  const int wr = w >> 2, wc = w & 3, lg = lane >> 4, lr = lane & 15;

#pragma unroll
  for (int m = 0; m < 8; ++m)
#pragma unroll
    for (int n = 0; n < 4; ++n) acc[m][n] = f32x4{0.f, 0.f, 0.f, 0.f};

  const u16* A1 = A + (size_t)128 * 2048;    // A half-1 rows
  const u16* B1 = B + (size_t)128 * 2048;    // B half-1 out-cols
  const int aoff = wr * 8192;                         // A read base (elems)
  const int boff = 16384 + ((wc >> 1) * 8192) + ((wc & 1) * 4096);

  // prologue: tile 0 -> buf0 (4 halves, 8 loads); cert; preload (0,W0) frags
  stage9(L,                 A,  0, tid);
  stage9(L + 8192,          A1, 0, tid);
  stage9(L + 16384,         B,  0, tid);
  stage9(L + 16384 + 8192,  B1, 0, tid);
  VM0();
  BARRIER();

  bf16x8 aRa[4], aRb[4], bR0[4], bR1[4];
  rd_a(aRa, L + aoff, 0, 0, lg, lr);
  rd_b(bR0, L + boff, 0, lg, lr);
  LGKM0();

#pragma unroll 1
  for (int t = 0; t < NKT - 1; ++t) {
    u16* Lc = L + ((t & 1) << 15);
    u16* Ln = L + (((t + 1) & 1) << 15);
    // ---- W0: stage A-h0',B-h0'; MFMA mq0(kg0); prefetch aR(mq1,kg0)
    stage9(Ln,                A,  t + 1, tid);
    stage9(Ln + 16384,        B,  t + 1, tid);
    BARRIER();
    rd_a(aRb, Lc + aoff, 0, 1, lg, lr);
    mmcl<SWAP>(acc, 0, aRa, bR0);
    LGKM0();
    // ---- W1: stage A-h1',B-h1'; MFMA mq1(kg0); prefetch aR(mq0,kg1)+bR(kg1)
    stage9(Ln + 8192,         A1, t + 1, tid);
    stage9(Ln + 16384 + 8192, B1, t + 1, tid);
    BARRIER();
    rd_a(aRa, Lc + aoff, 1, 0, lg, lr);
    rd_b(bR1, Lc + boff, 1, lg, lr);
    mmcl<SWAP>(acc, 1, aRb, bR0);
    LGKM0();
    // ---- W2: MFMA mq0(kg1); prefetch aR(mq1,kg1)
    BARRIER();
    rd_a(aRb, Lc + aoff, 1, 1, lg, lr);
    mmcl<SWAP>(acc, 0, aRa, bR1);
    LGKM0();
    // ---- W3: cert tile t+1; MFMA mq1(kg1); prefetch next tile (mq0,kg0)
    VM0();
    BARRIER();
    rd_a(aRa, Ln + aoff, 0, 0, lg, lr);
    rd_b(bR0, Ln + boff, 0, lg, lr);
    mmcl<SWAP>(acc, 1, aRb, bR1);
    LGKM0();
  }
  {  // peeled last tile (no staging, no next-tile prefetch)
    u16* Lc = L + (((NKT - 1) & 1) << 15);
    BARRIER();
    rd_a(aRb, Lc + aoff, 0, 1, lg, lr);
    mmcl<SWAP>(acc, 0, aRa, bR0);
    LGKM0();
    BARRIER();
    rd_a(aRa, Lc + aoff, 1, 0, lg, lr);
    rd_b(bR1, Lc + boff, 1, lg, lr);
    mmcl<SWAP>(acc, 1, aRb, bR0);
    LGKM0();
    BARRIER();
    rd_a(aRb, Lc + aoff, 1, 1, lg, lr);
    mmcl<SWAP>(acc, 0, aRa, bR1);
    LGKM0();
    BARRIER();
    mmcl<SWAP>(acc, 1, aRb, bR1);
  }
}

// ---------------------------------------------------------------------------
// GEMM1: qkvg = x_bf16 [16384,2048] @ WTcat^T [8192,2048], +bias.
// q,g (swapped-C) -> [s][2048], 8B stores (sigmoid on g);
// k,v (normal-C)  -> directly transposed [bh][d][s], 8B stores.
// grid: 2048 blocks (64 mt x 32 nt), 16x16 supergroups for L2.
// ---------------------------------------------------------------------------
__global__ __launch_bounds__(512, 2) void k_gemm_qkvg(
    const u16* __restrict__ xb, const u16* __restrict__ WT,
    const float* __restrict__ bias,
    u16* __restrict__ q, u16* __restrict__ kT, u16* __restrict__ vT,
    u16* __restrict__ g)
{
  __shared__ u16 L[65536];
  const int bid = blockIdx.x;
  const int grp = bid >> 8, r = bid & 255;
  const int mt = ((grp & 3) << 4) + (r & 15);
  const int nt = ((grp >> 2) << 4) + (r >> 4);
  const size_t bm0 = (size_t)mt << 8;
  const int    bn0 = nt << 8;
  const int nblk = bn0 >> 11;          // 0=q 1=k 2=v 3=g
  const int ocol0 = bn0 & 2047;

  const int tid = threadIdx.x, lane = tid & 63, w = tid >> 6;
  const int wr = w >> 2, wc = w & 3, lg = lane >> 4, lr = lane & 15;

  f32x4 acc[8][4];
  const u16* Ap = xb + bm0 * NHID;
  const u16* Bp = WT + (size_t)bn0 * NHID;

  if (nblk == 0 || nblk == 3) {
    gemm9<true>(Ap, Bp, acc, L);
    u16* outp = (nblk == 0) ? q : g;
    const bool sig = (nblk == 3);
#pragma unroll
    for (int m = 0; m < 8; ++m) {
      const size_t row = bm0 + (wr << 7) + (m << 4) + lr;
#pragma unroll
      for (int n = 0; n < 4; ++n) {
        const int colb = (wc << 6) + (n << 4) + (lg << 2);
        const float* bp = bias + bn0 + colb;
        u16x4 o;
#pragma unroll
        for (int j = 0; j < 4; ++j) {
          float val = acc[m][n][j] + bp[j];
          if (sig) val = 1.f / (1.f + __expf(-val));
          o[j] = f2bf(val);
        }
        *(u16x4*)(outp + row * NHID + ocol0 + colb) = o;
      }
    }
  } else {
    gemm9<false>(Ap, Bp, acc, L);
    u16* outp = (nblk == 1) ? kT : vT;
    const int b = (int)(bm0 >> 12);
    const int srow0 = (int)(bm0 & 4095) + (wr << 7) + (lg << 2);
#pragma unroll
    for (int m = 0; m < 8; ++m) {
      const int srow = srow0 + (m << 4);
#pragma unroll
      for (int n = 0; n < 4; ++n) {
        const int cg = ocol0 + (wc << 6) + (n << 4) + lr;  // col in [0,2048)
        const int h = cg >> 7, d = cg & 127;
        const float bia = bias[bn0 + (wc << 6) + (n << 4) + lr];
        u16x4 o;
#pragma unroll
        for (int j = 0; j < 4; ++j) o[j] = f2bf(acc[m][n][j] + bia);
        *(u16x4*)(outp + (((size_t)(b * NHEAD + h) * HDIM + d) << 12) + srow) = o;
      }
    }
  }
}

// ---------------------------------------------------------------------------
// out = attn @ WoT^T + bo (fp32, swapped-C -> float4 stores)
// grid: 512 blocks (64 mt x 8 nt), 16x8 supergroups
// ---------------------------------------------------------------------------
__global__ __launch_bounds__(512, 2) void k_gemm_out(
    const u16* __restrict__ attn, const u16* __restrict__ WoT,
    const float* __restrict__ bo, float* __restrict__ out)
{
  __shared__ u16 L[65536];
  const int bid = blockIdx.x;
  const int grp = bid >> 7, rr = bid & 127;
  const int mt = (grp << 4) + (rr & 15);
  const int nt = rr >> 4;
  const size_t bm0 = (size_t)mt << 8;
  const int    bn0 = nt << 8;

  const int tid = threadIdx.x, lane = tid & 63, w = tid >> 6;
  const int wr = w >> 2, wc = w & 3, lg = lane >> 4, lr = lane & 15;

  f32x4 acc[8][4];
  gemm9<true>(attn + bm0 * NHID, WoT + (size_t)bn0 * NHID, acc, L);

#pragma unroll
  for (int m = 0; m < 8; ++m) {
    const size_t row = bm0 + (wr << 7) + (m << 4) + lr;
#pragma unroll
    for (int n = 0; n < 4; ++n) {
      const int colb = bn0 + (wc << 6) + (n << 4) + (lg << 2);
      f32x4 o;
#pragma unroll
      for (int j = 0; j < 4; ++j) o[j] = acc[m][n][j] + bo[colb + j];
      *(f32x4*)(out + row * NHID + colb) = o;
    }
  }
}

// ===========================================================================
// Small 128x128 GEMM core (round-0 verified) for the tiny per-head GEMMs
// ===========================================================================
__device__ __forceinline__ void gemm_core(const u16* A, int lda,
                                          const u16* B, int ldb,
                                          int K, f32x4 acc[4][4],
                                          u16* As, u16* Bs)
{
  const int tid  = threadIdx.x;
  const int lane = tid & 63;
  const int w    = tid >> 6;
  const int wr   = (w >> 1) << 6;
  const int wc   = (w & 1) << 6;
  const int lg   = lane >> 4;
  const int lr   = lane & 15;

#pragma unroll
  for (int m = 0; m < 4; ++m)
#pragma unroll
    for (int n = 0; n < 4; ++n) acc[m][n] = f32x4{0.f, 0.f, 0.f, 0.f};

  for (int k0 = 0; k0 < K; k0 += 32) {
#pragma unroll
    for (int issue = 0; issue < 2; ++issue) {
      int c   = issue * 256 + tid;
      int row = c >> 2, cc = (c & 3) << 3;
      async_copy16(As + c * 8, A + (size_t)row * lda + k0 + cc);
    }
#pragma unroll
    for (int issue = 0; issue < 2; ++issue) {
      int c   = issue * 256 + tid;
      int row = c >> 2, cc = (c & 3) << 3;
      async_copy16(Bs + c * 8, B + (size_t)row * ldb + k0 + cc);
    }
    __syncthreads();

    bf16x8 af[4], bv[4];
#pragma unroll
    for (int m = 0; m < 4; ++m)
      af[m] = *(const bf16x8*)(As + ((wr + m * 16 + lr) << 5) + (lg << 3));
#pragma unroll
    for (int n = 0; n < 4; ++n)
      bv[n] = *(const bf16x8*)(Bs + ((wc + n * 16 + lr) << 5) + (lg << 3));

#pragma unroll
    for (int m = 0; m < 4; ++m)
#pragma unroll
      for (int n = 0; n < 4; ++n)
        acc[m][n] = __builtin_amdgcn_mfma_f32_16x16x32_bf16(af[m], bv[n], acc[m][n], 0, 0, 0);

    __syncthreads();
  }
}

// ---------------------------------------------------------------------------
// kv partial: C[e][d] = sum_{s chunk} vT[e][s]*kT[d][s]; grid (64 bh, 8 split)
// ---------------------------------------------------------------------------
__global__ __launch_bounds__(256) void k_gemm_kv(
    const u16* __restrict__ vT, const u16* __restrict__ kT, float* __restrict__ part)
{
  __shared__ u16 As[128 * 32];
  __shared__ u16 Bs[128 * 32];
  const int bh = blockIdx.x, sp = blockIdx.y;
  const u16* A  = vT + (size_t)bh * (HDIM * NS) + sp * 512;
  const u16* Bt = kT + (size_t)bh * (HDIM * NS) + sp * 512;
  f32x4 acc[4][4];
  gemm_core(A, NS, Bt, NS, 512, acc, As, Bs);

  float* outp = part + ((size_t)sp * 64 + bh) * 16384;
  const int tid = threadIdx.x, lane = tid & 63, w = tid >> 6;
  const int wr = (w >> 1) << 6, wc = (w & 1) << 6, lg = lane >> 4, lr = lane & 15;
#pragma unroll
  for (int m = 0; m < 4; ++m)
#pragma unroll
    for (int n = 0; n < 4; ++n) {
      const int col = wc + n * 16 + lr;
#pragma unroll
      for (int j = 0; j < 4; ++j) {
        const int row = wr + m * 16 + lg * 4 + j;
        outp[row * 128 + col] = acc[m][n][j];
      }
    }
}

// ---------------------------------------------------------------------------
// attn = (q @ kv) * g ; grid (32 stiles, 64 bh)
// ---------------------------------------------------------------------------
__global__ __launch_bounds__(256) void k_gemm_attn(
    const u16* __restrict__ q, const u16* __restrict__ kvT,
    const u16* __restrict__ g, u16* __restrict__ attn)
{
  __shared__ u16 As[128 * 32];
  __shared__ u16 Bs[128 * 32];
  const int st = blockIdx.x, bh = blockIdx.y;
  const int b = bh >> 4, h = bh & 15;
  const size_t bs0 = (size_t)b * NS + st * 128;
  f32x4 acc[4][4];
  gemm_core(q + bs0 * NHID + h * HDIM, NHID, kvT + (size_t)bh * 16384, HDIM, HDIM, acc, As, Bs);

  const int tid = threadIdx.x, lane = tid & 63, w = tid >> 6;
  const int wr = (w >> 1) << 6, wc = (w & 1) << 6, lg = lane >> 4, lr = lane & 15;
#pragma unroll
  for (int m = 0; m < 4; ++m)
#pragma unroll
    for (int n = 0; n < 4; ++n) {
      const int col = wc + n * 16 + lr;
#pragma unroll
      for (int j = 0; j < 4; ++j) {
        const int row = wr + m * 16 + lg * 4 + j;
        const size_t idx = (bs0 + row) * NHID + h * HDIM + col;
        attn[idx] = f2bf(acc[m][n][j] * bf2f(g[idx]));
      }
    }
}

// ---------------------------------------------------------------------------
// x fp32 -> bf16
// ---------------------------------------------------------------------------
__global__ __launch_bounds__(256) void k_cvt_x(const float* __restrict__ x, u16* __restrict__ xb)
{
  const size_t i = (size_t)blockIdx.x * 256 + threadIdx.x;
  const float4* xf = (const float4*)x;
  float4 a = xf[2 * i];
  float4 b = xf[2 * i + 1];
  u16x8 o;
  o[0] = f2bf(a.x); o[1] = f2bf(a.y); o[2] = f2bf(a.z); o[3] = f2bf(a.w);
  o[4] = f2bf(b.x); o[5] = f2bf(b.y); o[6] = f2bf(b.z); o[7] = f2bf(b.w);
  ((u16x8*)xb)[i] = o;
}

// ---------------------------------------------------------------------------
// W [2048][2048] fp32 -> WT bf16 transposed
// ---------------------------------------------------------------------------
__global__ __launch_bounds__(256) void k_cvt_w_t(const float* __restrict__ W, u16* __restrict__ WT)
{
  __shared__ u16 t[64][72];
  const int kt = blockIdx.x, nt = blockIdx.y;
  const int tid = threadIdx.x;
#pragma unroll
  for (int pass = 0; pass < 4; ++pass) {
    int c = pass * 256 + tid;
    int r = c >> 4, cc = (c & 15) << 2;
    float4 vv = *(const float4*)(W + (size_t)(kt * 64 + r) * 2048 + nt * 64 + cc);
    u16x4 o;
    o[0] = f2bf(vv.x); o[1] = f2bf(vv.y); o[2] = f2bf(vv.z); o[3] = f2bf(vv.w);
    *(u16x4*)&t[r][cc] = o;
  }
  __syncthreads();
#pragma unroll
  for (int pass = 0; pass < 2; ++pass) {
    int c = pass * 256 + tid;
    int rn = c >> 3, cs = (c & 7) << 3;
    u16x8 o;
#pragma unroll
    for (int j = 0; j < 8; ++j) o[j] = t[cs + j][rn];
    *(u16x8*)(WT + (size_t)(nt * 64 + rn) * 2048 + kt * 64 + cs) = o;
  }
}

// ---------------------------------------------------------------------------
__global__ __launch_bounds__(256) void k_bias_cat(
    const float* __restrict__ bq, const float* __restrict__ bk,
    const float* __restrict__ bv, const float* __restrict__ bg, float* __restrict__ o)
{
  const int i = blockIdx.x * 256 + threadIdx.x;  // 8192
  const int blk = i >> 11;
  const float* s = (blk == 0) ? bq : (blk == 1) ? bk : (blk == 2) ? bv : bg;
  o[i] = s[i & 2047];
}

__global__ __launch_bounds__(256) void k_kv_reduce(const float* __restrict__ part, u16* __restrict__ kvT)
{
  const int i = blockIdx.x * 256 + threadIdx.x;  // 1,048,576
  float s = 0.f;
#pragma unroll
  for (int sp = 0; sp < 8; ++sp) s += part[(size_t)sp * 1048576 + i];
  kvT[i] = f2bf(s);
}

// ---------------------------------------------------------------------------
extern "C" void kernel_launch(void* const* d_in, const int* in_sizes, int n_in,
                              void* d_out, int out_size, void* d_ws, size_t ws_size,
                              hipStream_t stream)
{
  const float* x  = (const float*)d_in[0];
  const float* Wq = (const float*)d_in[1];
  const float* bq = (const float*)d_in[2];
  const float* Wk = (const float*)d_in[3];
  const float* bk = (const float*)d_in[4];
  const float* Wv = (const float*)d_in[5];
  const float* bv = (const float*)d_in[6];
  const float* Wg = (const float*)d_in[7];
  const float* bg = (const float*)d_in[8];
  const float* Wo = (const float*)d_in[9];
  const float* bo = (const float*)d_in[10];
  float* out = (float*)d_out;

  char* ws = (char*)d_ws;
  u16*   xb   = (u16*)(ws + 0x00000000ULL);  // 64MB
  u16*   WT   = (u16*)(ws + 0x04000000ULL);  // 32MB  [Wq|Wk|Wv|Wg]^T bf16
  u16*   WoT  = (u16*)(ws + 0x06000000ULL);  // 8MB
  float* bias = (float*)(ws + 0x06800000ULL);// 32KB
  u16*   q    = (u16*)(ws + 0x06900000ULL);  // 64MB
  u16*   kT   = (u16*)(ws + 0x0A900000ULL);  // 64MB  [bh][d][s]
  u16*   vT   = (u16*)(ws + 0x0E900000ULL);  // 64MB  [bh][d][s]
  u16*   gg   = (u16*)(ws + 0x12900000ULL);  // 64MB
  u16*   kvT  = (u16*)(ws + 0x16900000ULL);  // 2MB
  // aliases (producer/consumer disjoint across sequential launches)
  float* part = (float*)WT;   // WT dead after qkvg (exactly 32MB)
  u16*   attn = xb;           // xb dead after qkvg

  if (ws_size < 0x16B00000ULL) return;

  k_cvt_x<<<16384, 256, 0, stream>>>(x, xb);
  k_cvt_w_t<<<dim3(32, 32), 256, 0, stream>>>(Wq, WT);
  k_cvt_w_t<<<dim3(32, 32), 256, 0, stream>>>(Wk, WT + (size_t)2048 * 2048);
  k_cvt_w_t<<<dim3(32, 32), 256, 0, stream>>>(Wv, WT + (size_t)2 * 2048 * 2048);
  k_cvt_w_t<<<dim3(32, 32), 256, 0, stream>>>(Wg, WT + (size_t)3 * 2048 * 2048);
  k_cvt_w_t<<<dim3(32, 32), 256, 0, stream>>>(Wo, WoT);
  k_bias_cat<<<32, 256, 0, stream>>>(bq, bk, bv, bg, bias);

  k_gemm_qkvg<<<2048, 512, 0, stream>>>(xb, WT, bias, q, kT, vT, gg);

  k_gemm_kv<<<dim3(64, 8), 256, 0, stream>>>(vT, kT, part);
  k_kv_reduce<<<4096, 256, 0, stream>>>(part, kvT);

  k_gemm_attn<<<dim3(32, 64), 256, 0, stream>>>(q, kvT, gg, attn);
  k_gemm_out<<<512, 512, 0, stream>>>(attn, WoT, bo, out);
}